// Round 3
// baseline (1567.137 us; speedup 1.0000x reference)
//
#include <hip/hip_runtime.h>
#include <hip/hip_bf16.h>
#include <math.h>

typedef __attribute__((ext_vector_type(8))) short bf16x8s;
typedef __attribute__((ext_vector_type(4))) float f32x4;

#define SEQ 2048
#define NTOK 8192
#define NQKV 3200   // 3072 qkv + 32 ab + 96 zero-pad

static __device__ __forceinline__ float bf2f(unsigned short u) {
  union { unsigned int i; float f; } c; c.i = ((unsigned int)u) << 16; return c.f;
}
static __device__ __forceinline__ unsigned short f2bf(float f) {
  union { float f; unsigned int i; } c; c.f = f;
  unsigned int x = c.i;
  return (unsigned short)((x + 0x7FFFu + ((x >> 16) & 1u)) >> 16);
}

static __device__ __forceinline__ float red16(float x) {
  union { float f; int i; } c, d;
  c.f = x; d.i = __builtin_amdgcn_update_dpp(0, c.i, 0xB1, 0xF, 0xF, true); x += d.f;
  c.f = x; d.i = __builtin_amdgcn_update_dpp(0, c.i, 0x4E, 0xF, 0xF, true); x += d.f;
  c.f = x; d.i = __builtin_amdgcn_update_dpp(0, c.i, 0x141, 0xF, 0xF, true); x += d.f;
  c.f = x; d.i = __builtin_amdgcn_update_dpp(0, c.i, 0x140, 0xF, 0xF, true); x += d.f;
  return x;
}

// ---------------------------------------------------------------- x cast fp32 -> bf16
__global__ __launch_bounds__(256) void castx_k(const float* __restrict__ in,
                                               unsigned short* __restrict__ out, int n4) {
  int i = blockIdx.x * 256 + threadIdx.x;
  if (i >= n4) return;
  float4 v = ((const float4*)in)[i];
  ushort4 o;
  o.x = f2bf(v.x); o.y = f2bf(v.y); o.z = f2bf(v.z); o.w = f2bf(v.w);
  ((ushort4*)out)[i] = o;
}

// ---------------------------------------------------------------- transpose fp32 -> bf16
__global__ void transpose_k(const float* __restrict__ in,
                            unsigned short* __restrict__ out, int R, int C) {
  __shared__ unsigned short tile[32][33];
  int c0 = blockIdx.x * 32, r0 = blockIdx.y * 32;
  int tx = threadIdx.x, ty = threadIdx.y;
  for (int i = ty; i < 32; i += 8)
    tile[i][tx] = f2bf(in[(size_t)(r0 + i) * C + c0 + tx]);
  __syncthreads();
  for (int i = ty; i < 32; i += 8)
    out[(size_t)(c0 + i) * R + r0 + tx] = tile[tx][i];
}

// ---------------------------------------------------------------- Wab^T rows (bf16) + zero pad
__global__ void build_wabT(const float* __restrict__ Wa,
                           const float* __restrict__ Wb,
                           unsigned short* __restrict__ rows) {
  int i = blockIdx.x * 256 + threadIdx.x;  // 128 * 1024
  int j = i >> 10, k = i & 1023;
  float v = 0.f;
  if (j < 16) v = Wa[k * 16 + j];
  else if (j < 32) v = Wb[k * 16 + (j - 16)];
  rows[(size_t)j * 1024 + k] = f2bf(v);
}

// ---------------------------------------------------------------- MFMA GEMM (m97 staging)
template<int MODE>
__global__ __launch_bounds__(256) void gemm_bt(const unsigned short* __restrict__ A,
                                               const unsigned short* __restrict__ Bt,
                                               void* __restrict__ Cv,
                                               int M, int N, int K,
                                               const float* __restrict__ ba,
                                               const float* __restrict__ bbp,
                                               float* __restrict__ alphaF,
                                               float* __restrict__ betaF) {
  __shared__ __align__(16) unsigned short As[128 * 32];
  __shared__ __align__(16) unsigned short Bs[128 * 32];
  int tiles_n = N >> 7;
  int tm = blockIdx.x / tiles_n, tn = blockIdx.x % tiles_n;
  int m0 = tm << 7, n0 = tn << 7;
  int tid = threadIdx.x;
  int wave = tid >> 6, lane = tid & 63;
  int wm = wave >> 1, wn = wave & 1;
  int r = lane & 15, qd = lane >> 4;
  int lr = lane >> 2, lc = lane & 3;

  f32x4 acc[4][4];
#pragma unroll
  for (int mi = 0; mi < 4; mi++)
#pragma unroll
    for (int ni = 0; ni < 4; ni++) acc[mi][ni] = (f32x4){0.f, 0.f, 0.f, 0.f};

  for (int k0 = 0; k0 < K; k0 += 32) {
#pragma unroll
    for (int gi = 0; gi < 2; ++gi) {
      int g = wave + gi * 4;
      int row = g * 16 + lr;
      const unsigned short* ga = A + (size_t)(m0 + row) * K + k0 + lc * 8;
      const unsigned short* gb = Bt + (size_t)(n0 + row) * K + k0 + lc * 8;
      __builtin_amdgcn_global_load_lds(
          (const __attribute__((address_space(1))) unsigned int*)ga,
          (__attribute__((address_space(3))) unsigned int*)(As + g * 512 + lane * 8),
          16, 0, 0);
      __builtin_amdgcn_global_load_lds(
          (const __attribute__((address_space(1))) unsigned int*)gb,
          (__attribute__((address_space(3))) unsigned int*)(Bs + g * 512 + lane * 8),
          16, 0, 0);
    }
    __syncthreads();
    bf16x8s af[4], bfr[4];
#pragma unroll
    for (int mi = 0; mi < 4; mi++)
      af[mi] = *(const bf16x8s*)&As[(wm * 64 + mi * 16 + r) * 32 + qd * 8];
#pragma unroll
    for (int ni = 0; ni < 4; ni++)
      bfr[ni] = *(const bf16x8s*)&Bs[(wn * 64 + ni * 16 + r) * 32 + qd * 8];
#pragma unroll
    for (int mi = 0; mi < 4; mi++)
#pragma unroll
      for (int ni = 0; ni < 4; ni++)
        acc[mi][ni] = __builtin_amdgcn_mfma_f32_16x16x32_bf16(af[mi], bfr[ni], acc[mi][ni], 0, 0, 0);
    __syncthreads();
  }

  bool qk = (MODE == 2) && (n0 < 2048);
#pragma unroll
  for (int mi = 0; mi < 4; mi++) {
    f32x4 sc = (f32x4){1.f, 1.f, 1.f, 1.f};
    if (qk) {
      f32x4 ss = acc[mi][0] * acc[mi][0] + acc[mi][1] * acc[mi][1]
               + acc[mi][2] * acc[mi][2] + acc[mi][3] * acc[mi][3];
#pragma unroll
      for (int cc = 0; cc < 4; cc++) {
        float s = red16(ss[cc]);
        sc[cc] = 1.f / fmaxf(sqrtf(s), 1e-12f);
      }
    }
#pragma unroll
    for (int ni = 0; ni < 4; ni++)
#pragma unroll
      for (int reg = 0; reg < 4; reg++) {
        int m = m0 + wm * 64 + mi * 16 + qd * 4 + reg;
        int n = n0 + wn * 64 + ni * 16 + r;
        float a = acc[mi][ni][reg];
        if (MODE == 0) ((unsigned short*)Cv)[(size_t)m * N + n] = f2bf(a);
        else if (MODE == 1) ((float*)Cv)[(size_t)m * N + n] = a;
        else {
          if (qk) a *= sc[reg];
          if (n < 3072) ((unsigned short*)Cv)[(size_t)m * 3072 + n] = f2bf(a);
          else if (n < 3104) {
            int j = n - 3072;
            float bias = (j < 16) ? ba[j] : bbp[j - 16];
            float s = 1.f / (1.f + expf(-(a + bias)));
            if (j < 16) alphaF[(size_t)m * 16 + j] = s;
            else        betaF[(size_t)m * 16 + (j - 16)] = s;
          }
        }
      }
  }
}

// ================================================================ chunked delta-rule scan
// 64 blocks = (b,h); 512 thr = 8 waves. Chunk L=32, 64 chunks sequential.
// Rebalanced 3-phase schedule:
//  P1(c): W(c)=K*S_in, U(c)=Q*S_in, KT(c) build          (consumers of ST)
//  P2(c): fwd-sub(c) | stage(c+2) issue | ab(c+2) | Y(c-1)  (long phase hides HBM)
//  P3(c): S-update(c), Gram(c+1)
// LDS padded: W/U rows 66 f32, G/KT rows 40 bf16, Mt rows 36 f32.
#define L_ST_HI 0        // bf16 [64 e][64 d] swz      8192
#define L_ST_LO 8192     //                            8192
#define L_K     16384    // 2 x [32 t][64 d] swz bf16  8192
#define L_Q     24576    //                            8192
#define L_V     32768    // 3 x [32 t][64 e] swz bf16 12288
#define L_KT    45056    // bf16 [64 d][40 i]          5120
#define L_MT    50176    // 2 x f32 [32 i][36 t]       9216
#define L_G     59392    // 2 x bf16 [32 t][40 i]      6400
#define L_CTHI  65792    // 2 x bf16 [64 e][40 i]     10240
#define L_CTLO  76032    //                           10240
#define L_W     86272    // f32 [32 t][66 e]           8448
#define L_U     94720    // 2 x f32 [32 t][66 e]      16896
#define L_AB    111616   // f32 [4][136]               2176
#define L_SIZE  113792
// ab slot (136 floats): EPREV 0..31, EINC 32..63, EINV 64..95, B 96..127, E31 @128

static __device__ __forceinline__ float rdlane(float v, int i) {
  return __int_as_float(__builtin_amdgcn_readlane(__float_as_int(v), i));
}

__global__ __launch_bounds__(512, 2) void dscan_k(const unsigned short* __restrict__ qkv,
                                                  const float* __restrict__ alphaF,
                                                  const float* __restrict__ betaF,
                                                  unsigned short* __restrict__ y) {
  extern __shared__ char smem[];
  const int bh = blockIdx.x;
  const int b = bh >> 4, h = bh & 15;
  const int tid = threadIdx.x, wid = tid >> 6, lane = tid & 63;
  const int r = lane & 15, qd = lane >> 4;

  float* abf = (float*)(smem + L_AB);

  // stage chunk cn: waves 1-4 load K+V parts, waves 4-7 load Q parts; wid0 free.
  auto stage_issue = [&](int cn) {
    int bk = cn & 1, bv3 = cn % 3;
    int tok0 = b * SEQ + cn * 32;
    int row = lane >> 3, s8 = lane & 7;
    int sx = ((s8 ^ (row & 7)) * 8);
    if (wid >= 1 && wid <= 4) {
      int p = wid - 1;
      const unsigned short* srck = qkv + (size_t)(tok0 + p * 8 + row) * 3072 + 1024 + h * 64 + sx;
      unsigned short* dstk = (unsigned short*)(smem + L_K + bk * 4096 + p * 1024) + lane * 8;
      __builtin_amdgcn_global_load_lds(
          (const __attribute__((address_space(1))) unsigned int*)srck,
          (__attribute__((address_space(3))) unsigned int*)dstk, 16, 0, 0);
      const unsigned short* srcv = qkv + (size_t)(tok0 + p * 8 + row) * 3072 + 2048 + h * 64 + sx;
      unsigned short* dstv = (unsigned short*)(smem + L_V + bv3 * 4096 + p * 1024) + lane * 8;
      __builtin_amdgcn_global_load_lds(
          (const __attribute__((address_space(1))) unsigned int*)srcv,
          (__attribute__((address_space(3))) unsigned int*)dstv, 16, 0, 0);
    }
    if (wid >= 4) {
      int p = (wid == 4) ? 3 : (wid - 5);
      const unsigned short* srcq = qkv + (size_t)(tok0 + p * 8 + row) * 3072 + h * 64 + sx;
      unsigned short* dstq = (unsigned short*)(smem + L_Q + bk * 4096 + p * 1024) + lane * 8;
      __builtin_amdgcn_global_load_lds(
          (const __attribute__((address_space(1))) unsigned int*)srcq,
          (__attribute__((address_space(3))) unsigned int*)dstq, 16, 0, 0);
    }
  };

  auto ab_compute = [&](int cn) {
    int t = lane & 31;
    int tok = b * SEQ + cn * 32 + t;
    float av = alphaF[(size_t)tok * 16 + h];
    float bv = betaF[(size_t)tok * 16 + h];
    float p = av;
#pragma unroll
    for (int s = 1; s < 32; s <<= 1) {
      float o = __shfl_up(p, s, 32);
      if ((lane & 31) >= s) p *= o;
    }
    float ep = __shfl_up(p, 1, 32);
    if ((lane & 31) == 0) ep = 1.f;
    float* ap = abf + (cn & 3) * 136;
    if (lane < 32) {
      ap[0 + t] = ep;
      ap[32 + t] = p;
      ap[64 + t] = 1.0f / p;
      if (t == 31) ap[128] = p;
    } else {
      ap[96 + t] = bv;
    }
  };

  // Gram for chunk cn: wid3,4 -> KK -> Mt[cn&1]; wid5,6 -> KQ -> G[cn&1]
  auto gram_do = [&](int cn) {
    if (wid < 3 || wid > 6) return;
    int buf = cn & 1;
    const char* Kn = smem + L_K + buf * 4096;
    const char* Qn = smem + L_Q + buf * 4096;
    const float* ap = abf + (cn & 3) * 136;
    bool kk = (wid <= 4);
    int g0 = (kk ? (wid - 3) : (wid - 5)) * 2;
#pragma unroll
    for (int j = 0; j < 2; ++j) {
      int g = g0 + j, gi = g >> 1, gt = g & 1;
      f32x4 acc = (f32x4){0.f, 0.f, 0.f, 0.f};
#pragma unroll
      for (int ks = 0; ks < 2; ++ks) {
        int o = ks * 64 + qd * 16;
        bf16x8s af = *(const bf16x8s*)(Kn + (gi * 16 + r) * 128 + (o ^ ((r & 7) << 4)));
        bf16x8s bf = kk
            ? *(const bf16x8s*)(Kn + (gt * 16 + r) * 128 + (o ^ ((r & 7) << 4)))
            : *(const bf16x8s*)(Qn + (gt * 16 + r) * 128 + (o ^ ((r & 7) << 4)));
        acc = __builtin_amdgcn_mfma_f32_16x16x32_bf16(af, bf, acc, 0, 0, 0);
      }
      int tl = gt * 16 + r;
      f32x4 ei4 = *(const f32x4*)&ap[64 + gi * 16 + qd * 4];
      if (kk) {
        float bt = ap[96 + tl], ept = ap[0 + tl];
        float* Mtp = (float*)(smem + L_MT + buf * 4608);
#pragma unroll
        for (int reg = 0; reg < 4; ++reg) {
          int i = gi * 16 + qd * 4 + reg;
          Mtp[i * 36 + tl] = (i < tl) ? bt * ept * ei4[reg] * acc[reg] : 0.f;
        }
      } else {
        float et = ap[32 + tl];
        unsigned short* Gp = (unsigned short*)(smem + L_G + buf * 3200);
#pragma unroll
        for (int reg = 0; reg < 4; ++reg) {
          int i = gi * 16 + qd * 4 + reg;
          float v = (i <= tl) ? et * ei4[reg] * acc[reg] : 0.f;
          Gp[tl * 40 + i] = f2bf(v);
        }
      }
    }
  };

  // Y(cc) = diag(einc)*U + G*C ; waves 2..5, 2 tiles each
  auto y_do = [&](int cc) {
    if (wid < 2 || wid > 5) return;
    int buf = cc & 1;
    const char* Gp = smem + L_G + buf * 3200;
    const float* Up = (const float*)(smem + L_U + buf * 8448);
    const float* ap = abf + (cc & 3) * 136;
#pragma unroll
    for (int j = 0; j < 2; ++j) {
      int idx = (wid - 2) * 2 + j;
      int ty = idx >> 2, te = idx & 3;
      bf16x8s af = *(const bf16x8s*)(Gp + (ty * 16 + r) * 80 + qd * 16);
      bf16x8s bhv = *(const bf16x8s*)(smem + L_CTHI + buf * 5120 + (te * 16 + r) * 80 + qd * 16);
      bf16x8s blv = *(const bf16x8s*)(smem + L_CTLO + buf * 5120 + (te * 16 + r) * 80 + qd * 16);
      f32x4 acc = (f32x4){0.f, 0.f, 0.f, 0.f};
      acc = __builtin_amdgcn_mfma_f32_16x16x32_bf16(af, bhv, acc, 0, 0, 0);
      acc = __builtin_amdgcn_mfma_f32_16x16x32_bf16(af, blv, acc, 0, 0, 0);
      f32x4 e4 = *(const f32x4*)&ap[32 + ty * 16 + qd * 4];
#pragma unroll
      for (int reg = 0; reg < 4; ++reg) {
        int t = ty * 16 + qd * 4 + reg, e = te * 16 + r;
        float yv = fmaf(e4[reg], Up[t * 66 + e], acc[reg]);
        y[(size_t)(b * SEQ + cc * 32 + t) * 1024 + h * 64 + e] = f2bf(yv);
      }
    }
  };

  // S master in registers: tiles s = wid*2 + j
  float sreg[8];
#pragma unroll
  for (int i = 0; i < 8; ++i) sreg[i] = 0.f;

  // ---------------- prologue ----------------
  {
    uint4 z = (uint4){0u, 0u, 0u, 0u};
    *(uint4*)(smem + L_ST_HI + tid * 16) = z;
    *(uint4*)(smem + L_ST_LO + tid * 16) = z;
  }
  stage_issue(0);
  stage_issue(1);
  if (wid == 0) ab_compute(0);
  else if (wid == 1) ab_compute(1);
  __syncthreads();
  gram_do(0);
  __syncthreads();

  const char* SThi = smem + L_ST_HI;
  const char* STlo = smem + L_ST_LO;

  for (int c = 0; c < 64; ++c) {
    const int cbuf = c & 1, cs = c & 3;
    // ======== P1: W(c), U(c), KT(c) ========
    {
      int tt = wid >> 2, te = wid & 3;
      const char* Kc = smem + L_K + cbuf * 4096;
      const char* Qc = smem + L_Q + cbuf * 4096;
      f32x4 accw = (f32x4){0.f, 0.f, 0.f, 0.f};
      f32x4 accu = (f32x4){0.f, 0.f, 0.f, 0.f};
#pragma unroll
      for (int ks = 0; ks < 2; ++ks) {
        int o = ks * 64 + qd * 16;
        bf16x8s bhv = *(const bf16x8s*)(SThi + (te * 16 + r) * 128 + (o ^ ((r & 7) << 4)));
        bf16x8s blv = *(const bf16x8s*)(STlo + (te * 16 + r) * 128 + (o ^ ((r & 7) << 4)));
        bf16x8s afk = *(const bf16x8s*)(Kc + (tt * 16 + r) * 128 + (o ^ ((r & 7) << 4)));
        bf16x8s afq = *(const bf16x8s*)(Qc + (tt * 16 + r) * 128 + (o ^ ((r & 7) << 4)));
        accw = __builtin_amdgcn_mfma_f32_16x16x32_bf16(afk, bhv, accw, 0, 0, 0);
        accw = __builtin_amdgcn_mfma_f32_16x16x32_bf16(afk, blv, accw, 0, 0, 0);
        accu = __builtin_amdgcn_mfma_f32_16x16x32_bf16(afq, bhv, accu, 0, 0, 0);
        accu = __builtin_amdgcn_mfma_f32_16x16x32_bf16(afq, blv, accu, 0, 0, 0);
      }
      float* Wp = (float*)(smem + L_W);
      float* Up = (float*)(smem + L_U + cbuf * 8448);
#pragma unroll
      for (int reg = 0; reg < 4; ++reg) {
        Wp[(tt * 16 + qd * 4 + reg) * 66 + te * 16 + r] = accw[reg];
        Up[(tt * 16 + qd * 4 + reg) * 66 + te * 16 + r] = accu[reg];
      }
    }
    if (wid == 5 || wid == 6) {
      // KT[d][i] = K[i][d] * e31 * einv[i]; wid5: i 0..15, wid6: i 16..31
      const float* ap = abf + cs * 136;
      float vei = ap[64 + (lane & 31)];
      float e31 = ap[128];
      const char* Kc = smem + L_K + cbuf * 4096;
      int i0 = (wid - 5) * 16;
      unsigned int pk[8];
#pragma unroll
      for (int ii = 0; ii < 16; ++ii) {
        int i = i0 + ii;
        unsigned short kv = *(const unsigned short*)(Kc + (i * 128 + ((lane * 2) ^ ((i & 7) << 4))));
        float f = bf2f(kv) * (e31 * rdlane(vei, i));
        unsigned short o = f2bf(f);
        if (ii & 1) pk[ii >> 1] |= ((unsigned int)o << 16);
        else        pk[ii >> 1] = o;
      }
      char* KTp = smem + L_KT + lane * 80 + i0 * 2;
      *(uint4*)(KTp)      = (uint4){pk[0], pk[1], pk[2], pk[3]};
      *(uint4*)(KTp + 16) = (uint4){pk[4], pk[5], pk[6], pk[7]};
    }
    __syncthreads();

    // ======== P2: stage(c+2) | fwd-sub(c) | ab(c+2) | Y(c-1) ========
    if (c + 2 < 64) stage_issue(c + 2);
    if (wid == 0) {
      __builtin_amdgcn_s_setprio(1);
      const float* Wp = (const float*)(smem + L_W);
      const char* Vb = smem + L_V + (c % 3) * 4096;
      const float* ap = abf + cs * 136;
      float vb = ap[96 + (lane & 31)];
      float vep = ap[0 + (lane & 31)];
      float d_[32], r_[32];
#pragma unroll
      for (int i = 0; i < 32; ++i) r_[i] = 0.f;
#pragma unroll
      for (int i = 0; i < 32; ++i) {
        float w = Wp[i * 66 + lane];
        unsigned short vx = *(const unsigned short*)(Vb + (i * 128 + ((lane * 2) ^ ((i & 7) << 4))));
        d_[i] = rdlane(vb, i) * fmaf(-rdlane(vep, i), w, bf2f(vx));
      }
      const float* Mtp = (const float*)(smem + L_MT + cbuf * 4608);
#pragma unroll
      for (int i = 0; i < 32; ++i) {
        float cv = d_[i] - r_[i];
        d_[i] = cv;
#pragma unroll
        for (int cb4 = 0; cb4 < 8; ++cb4) {
          if (cb4 * 4 + 3 > i) {
            f32x4 m4 = *(const f32x4*)&Mtp[i * 36 + cb4 * 4];
            r_[cb4 * 4 + 0] = fmaf(m4[0], cv, r_[cb4 * 4 + 0]);
            r_[cb4 * 4 + 1] = fmaf(m4[1], cv, r_[cb4 * 4 + 1]);
            r_[cb4 * 4 + 2] = fmaf(m4[2], cv, r_[cb4 * 4 + 2]);
            r_[cb4 * 4 + 3] = fmaf(m4[3], cv, r_[cb4 * 4 + 3]);
          }
        }
      }
      __builtin_amdgcn_s_setprio(0);
      unsigned int ph[16], pl[16];
#pragma unroll
      for (int j = 0; j < 16; ++j) {
        unsigned short h0 = f2bf(d_[2 * j]), h1 = f2bf(d_[2 * j + 1]);
        ph[j] = (unsigned int)h0 | ((unsigned int)h1 << 16);
        float l0 = d_[2 * j] - bf2f(h0), l1 = d_[2 * j + 1] - bf2f(h1);
        pl[j] = (unsigned int)f2bf(l0) | ((unsigned int)f2bf(l1) << 16);
      }
      char* Ch = smem + L_CTHI + cbuf * 5120 + lane * 80;
      char* Cl = smem + L_CTLO + cbuf * 5120 + lane * 80;
#pragma unroll
      for (int k = 0; k < 4; ++k) {
        *(uint4*)(Ch + k * 16) = (uint4){ph[4 * k], ph[4 * k + 1], ph[4 * k + 2], ph[4 * k + 3]};
        *(uint4*)(Cl + k * 16) = (uint4){pl[4 * k], pl[4 * k + 1], pl[4 * k + 2], pl[4 * k + 3]};
      }
    }
    if (wid == 1 && c + 2 < 64) ab_compute(c + 2);
    if (c >= 1) y_do(c - 1);
    __syncthreads();

    // ======== P3: S-update(c), Gram(c+1) ========
    {
      float e31 = abf[cs * 136 + 128];
      const char* KT = smem + L_KT;
#pragma unroll
      for (int j = 0; j < 2; ++j) {
        int s = wid * 2 + j, td = s >> 2, te = s & 3;
        bf16x8s af = *(const bf16x8s*)(KT + (td * 16 + r) * 80 + qd * 16);
        bf16x8s bhv = *(const bf16x8s*)(smem + L_CTHI + cbuf * 5120 + (te * 16 + r) * 80 + qd * 16);
        bf16x8s blv = *(const bf16x8s*)(smem + L_CTLO + cbuf * 5120 + (te * 16 + r) * 80 + qd * 16);
        f32x4 acc = (f32x4){0.f, 0.f, 0.f, 0.f};
        acc = __builtin_amdgcn_mfma_f32_16x16x32_bf16(af, bhv, acc, 0, 0, 0);
        acc = __builtin_amdgcn_mfma_f32_16x16x32_bf16(af, blv, acc, 0, 0, 0);
#pragma unroll
        for (int reg = 0; reg < 4; ++reg) {
          int d = td * 16 + qd * 4 + reg, e = te * 16 + r;
          float sv = fmaf(e31, sreg[j * 4 + reg], acc[reg]);
          sreg[j * 4 + reg] = sv;
          unsigned short hi = f2bf(sv);
          float lo = sv - bf2f(hi);
          *(unsigned short*)(smem + L_ST_HI + e * 128 + ((d * 2) ^ ((e & 7) << 4))) = hi;
          *(unsigned short*)(smem + L_ST_LO + e * 128 + ((d * 2) ^ ((e & 7) << 4))) = f2bf(lo);
        }
      }
    }
    if (c + 1 < 64) gram_do(c + 1);
    __syncthreads();
  }

  // -------- epilogue: Y(63) --------
  y_do(63);
}

// ---------------------------------------------------------------- rmsnorm*gate
__global__ __launch_bounds__(256) void rmsgate_k(const unsigned short* __restrict__ y,
                                                 const unsigned short* __restrict__ gl,
                                                 const float* __restrict__ gnorm,
                                                 unsigned short* __restrict__ z) {
  __shared__ float red[4];
  int row = blockIdx.x, tid = threadIdx.x;
  size_t base = (size_t)row * 1024 + tid * 4;
  uint2 yv = *(const uint2*)&y[base];
  float f0 = bf2f((unsigned short)(yv.x & 0xffff)), f1 = bf2f((unsigned short)(yv.x >> 16));
  float f2 = bf2f((unsigned short)(yv.y & 0xffff)), f3 = bf2f((unsigned short)(yv.y >> 16));
  float ss = f0 * f0 + f1 * f1 + f2 * f2 + f3 * f3;
#pragma unroll
  for (int s = 1; s < 64; s <<= 1) ss += __shfl_xor(ss, s);
  if ((tid & 63) == 0) red[tid >> 6] = ss;
  __syncthreads();
  ss = red[0] + red[1] + red[2] + red[3];
  float rms = rsqrtf(ss * (1.0f / 1024.0f) + 1e-5f);
  uint2 gv = *(const uint2*)&gl[base];
  float4 gn = *(const float4*)&gnorm[tid * 4];
  float g[4] = {bf2f((unsigned short)(gv.x & 0xffff)), bf2f((unsigned short)(gv.x >> 16)),
                bf2f((unsigned short)(gv.y & 0xffff)), bf2f((unsigned short)(gv.y >> 16))};
  float gnv[4] = {gn.x, gn.y, gn.z, gn.w};
  float fv[4] = {f0, f1, f2, f3};
  unsigned short o[4];
#pragma unroll
  for (int jj = 0; jj < 4; jj++) {
    float gate = g[jj] / (1.f + expf(-g[jj]));
    o[jj] = f2bf(fv[jj] * rms * gnv[jj] * gate);
  }
  uint2 ov;
  ov.x = (unsigned int)o[0] | ((unsigned int)o[1] << 16);
  ov.y = (unsigned int)o[2] | ((unsigned int)o[3] << 16);
  *(uint2*)&z[base] = ov;
}

// ---------------------------------------------------------------- launch
extern "C" void kernel_launch(void* const* d_in, const int* in_sizes, int n_in,
                              void* d_out, int out_size, void* d_ws, size_t ws_size,
                              hipStream_t stream) {
  const float* x     = (const float*)d_in[0];
  const float* Wq    = (const float*)d_in[1];
  const float* Wk    = (const float*)d_in[2];
  const float* Wv    = (const float*)d_in[3];
  const float* Wa    = (const float*)d_in[4];
  const float* ba    = (const float*)d_in[5];
  const float* Wb    = (const float*)d_in[6];
  const float* bb    = (const float*)d_in[7];
  const float* Wg    = (const float*)d_in[8];
  const float* Wo    = (const float*)d_in[9];
  const float* gnorm = (const float*)d_in[10];
  float* out = (float*)d_out;

  unsigned short* xbf    = (unsigned short*)d_ws;                 // 8192*1024
  unsigned short* Bt_qkv = xbf + (size_t)NTOK * 1024;             // 3200*1024
  unsigned short* Bt_g   = Bt_qkv + (size_t)NQKV * 1024;          // 1024*1024
  unsigned short* Bt_o   = Bt_g + (size_t)1024 * 1024;            // 1024*1024
  unsigned short* qkv    = Bt_o + (size_t)1024 * 1024;            // 8192*3072
  unsigned short* gatelin= qkv + (size_t)NTOK * 3072;             // 8192*1024
  unsigned short* ybuf   = gatelin + (size_t)NTOK * 1024;         // 8192*1024
  float* alphaF          = (float*)(ybuf + (size_t)NTOK * 1024);  // 8192*16
  float* betaF           = alphaF + (size_t)NTOK * 16;            // 8192*16
  unsigned short* zbuf   = xbf;  // alias: xbf dead after gate GEMM

  static int dscan_inited = 0;
  if (!dscan_inited) {
    hipFuncSetAttribute((const void*)dscan_k,
                        hipFuncAttributeMaxDynamicSharedMemorySize, L_SIZE);
    dscan_inited = 1;
  }

  castx_k<<<NTOK * 1024 / 4 / 256, 256, 0, stream>>>(x, xbf, NTOK * 1024 / 4);
  dim3 tb(32, 8);
  transpose_k<<<dim3(32, 32), tb, 0, stream>>>(Wq, Bt_qkv, 1024, 1024);
  transpose_k<<<dim3(32, 32), tb, 0, stream>>>(Wk, Bt_qkv + (size_t)1024 * 1024, 1024, 1024);
  transpose_k<<<dim3(32, 32), tb, 0, stream>>>(Wv, Bt_qkv + (size_t)2048 * 1024, 1024, 1024);
  transpose_k<<<dim3(32, 32), tb, 0, stream>>>(Wg, Bt_g, 1024, 1024);
  transpose_k<<<dim3(32, 32), tb, 0, stream>>>(Wo, Bt_o, 1024, 1024);
  build_wabT<<<512, 256, 0, stream>>>(Wa, Wb, Bt_qkv + (size_t)3072 * 1024);

  gemm_bt<2><<<(NTOK / 128) * (NQKV / 128), 256, 0, stream>>>(
      xbf, Bt_qkv, qkv, NTOK, NQKV, 1024, ba, bb, alphaF, betaF);
  gemm_bt<0><<<(NTOK / 128) * (1024 / 128), 256, 0, stream>>>(
      xbf, Bt_g, gatelin, NTOK, 1024, 1024, nullptr, nullptr, nullptr, nullptr);
  dscan_k<<<64, 512, L_SIZE, stream>>>(qkv, alphaF, betaF, ybuf);
  rmsgate_k<<<NTOK, 256, 0, stream>>>(ybuf, gatelin, gnorm, zbuf);
  gemm_bt<1><<<(NTOK / 128) * (1024 / 128), 256, 0, stream>>>(
      zbuf, Bt_o, out, NTOK, 1024, 1024, nullptr, nullptr, nullptr, nullptr);
}

// Round 5
// 515.389 us; speedup vs baseline: 3.0407x; 3.0407x over previous
//
#include <hip/hip_runtime.h>
#include <hip/hip_bf16.h>
#include <math.h>

typedef __attribute__((ext_vector_type(8))) short bf16x8s;
typedef __attribute__((ext_vector_type(4))) float f32x4;

#define SEQ 2048
#define NTOK 8192
#define NQKV 3200   // 3072 qkv + 32 ab + 96 zero-pad
#define NUNIT 4096  // 64 bh * 64 chunks

static __device__ __forceinline__ float bf2f(unsigned short u) {
  union { unsigned int i; float f; } c; c.i = ((unsigned int)u) << 16; return c.f;
}
static __device__ __forceinline__ unsigned short f2bf(float f) {
  union { float f; unsigned int i; } c; c.f = f;
  unsigned int x = c.i;
  return (unsigned short)((x + 0x7FFFu + ((x >> 16) & 1u)) >> 16);
}

static __device__ __forceinline__ float red16(float x) {
  union { float f; int i; } c, d;
  c.f = x; d.i = __builtin_amdgcn_update_dpp(0, c.i, 0xB1, 0xF, 0xF, true); x += d.f;
  c.f = x; d.i = __builtin_amdgcn_update_dpp(0, c.i, 0x4E, 0xF, 0xF, true); x += d.f;
  c.f = x; d.i = __builtin_amdgcn_update_dpp(0, c.i, 0x141, 0xF, 0xF, true); x += d.f;
  c.f = x; d.i = __builtin_amdgcn_update_dpp(0, c.i, 0x140, 0xF, 0xF, true); x += d.f;
  return x;
}

static __device__ __forceinline__ float rdlane(float v, int i) {
  return __int_as_float(__builtin_amdgcn_readlane(__float_as_int(v), i));
}

#define GLD16(SRC, DST) __builtin_amdgcn_global_load_lds( \
    (const __attribute__((address_space(1))) unsigned int*)(SRC), \
    (__attribute__((address_space(3))) unsigned int*)(DST), 16, 0, 0)
#define GLD4(SRC, DST) __builtin_amdgcn_global_load_lds( \
    (const __attribute__((address_space(1))) unsigned int*)(SRC), \
    (__attribute__((address_space(3))) unsigned int*)(DST), 4, 0, 0)

// ---------------------------------------------------------------- x cast fp32 -> bf16
__global__ __launch_bounds__(256) void castx_k(const float* __restrict__ in,
                                               unsigned short* __restrict__ out, int n4) {
  int i = blockIdx.x * 256 + threadIdx.x;
  if (i >= n4) return;
  float4 v = ((const float4*)in)[i];
  ushort4 o;
  o.x = f2bf(v.x); o.y = f2bf(v.y); o.z = f2bf(v.z); o.w = f2bf(v.w);
  ((ushort4*)out)[i] = o;
}

// ---------------------------------------------------------------- transpose fp32 -> bf16
__global__ void transpose_k(const float* __restrict__ in,
                            unsigned short* __restrict__ out, int R, int C) {
  __shared__ unsigned short tile[32][33];
  int c0 = blockIdx.x * 32, r0 = blockIdx.y * 32;
  int tx = threadIdx.x, ty = threadIdx.y;
  for (int i = ty; i < 32; i += 8)
    tile[i][tx] = f2bf(in[(size_t)(r0 + i) * C + c0 + tx]);
  __syncthreads();
  for (int i = ty; i < 32; i += 8)
    out[(size_t)(c0 + i) * R + r0 + tx] = tile[tx][i];
}

// ---------------------------------------------------------------- Wab^T rows (bf16) + zero pad
__global__ void build_wabT(const float* __restrict__ Wa,
                           const float* __restrict__ Wb,
                           unsigned short* __restrict__ rows) {
  int i = blockIdx.x * 256 + threadIdx.x;  // 128 * 1024
  int j = i >> 10, k = i & 1023;
  float v = 0.f;
  if (j < 16) v = Wa[k * 16 + j];
  else if (j < 32) v = Wb[k * 16 + (j - 16)];
  rows[(size_t)j * 1024 + k] = f2bf(v);
}

// ---------------------------------------------------------------- MFMA GEMM (m97 staging)
template<int MODE>
__global__ __launch_bounds__(256) void gemm_bt(const unsigned short* __restrict__ A,
                                               const unsigned short* __restrict__ Bt,
                                               void* __restrict__ Cv,
                                               int M, int N, int K,
                                               const float* __restrict__ ba,
                                               const float* __restrict__ bbp,
                                               float* __restrict__ alphaF,
                                               float* __restrict__ betaF) {
  __shared__ __align__(16) unsigned short As[128 * 32];
  __shared__ __align__(16) unsigned short Bs[128 * 32];
  int tiles_n = N >> 7;
  int tm = blockIdx.x / tiles_n, tn = blockIdx.x % tiles_n;
  int m0 = tm << 7, n0 = tn << 7;
  int tid = threadIdx.x;
  int wave = tid >> 6, lane = tid & 63;
  int wm = wave >> 1, wn = wave & 1;
  int r = lane & 15, qd = lane >> 4;
  int lr = lane >> 2, lc = lane & 3;

  f32x4 acc[4][4];
#pragma unroll
  for (int mi = 0; mi < 4; mi++)
#pragma unroll
    for (int ni = 0; ni < 4; ni++) acc[mi][ni] = (f32x4){0.f, 0.f, 0.f, 0.f};

  for (int k0 = 0; k0 < K; k0 += 32) {
#pragma unroll
    for (int gi = 0; gi < 2; ++gi) {
      int g = wave + gi * 4;
      int row = g * 16 + lr;
      const unsigned short* ga = A + (size_t)(m0 + row) * K + k0 + lc * 8;
      const unsigned short* gb = Bt + (size_t)(n0 + row) * K + k0 + lc * 8;
      GLD16(ga, As + g * 512 + lane * 8);
      GLD16(gb, Bs + g * 512 + lane * 8);
    }
    __syncthreads();
    bf16x8s af[4], bfr[4];
#pragma unroll
    for (int mi = 0; mi < 4; mi++)
      af[mi] = *(const bf16x8s*)&As[(wm * 64 + mi * 16 + r) * 32 + qd * 8];
#pragma unroll
    for (int ni = 0; ni < 4; ni++)
      bfr[ni] = *(const bf16x8s*)&Bs[(wn * 64 + ni * 16 + r) * 32 + qd * 8];
#pragma unroll
    for (int mi = 0; mi < 4; mi++)
#pragma unroll
      for (int ni = 0; ni < 4; ni++)
        acc[mi][ni] = __builtin_amdgcn_mfma_f32_16x16x32_bf16(af[mi], bfr[ni], acc[mi][ni], 0, 0, 0);
    __syncthreads();
  }

  bool qk = (MODE == 2) && (n0 < 2048);
#pragma unroll
  for (int mi = 0; mi < 4; mi++) {
    f32x4 sc = (f32x4){1.f, 1.f, 1.f, 1.f};
    if (qk) {
      f32x4 ss = acc[mi][0] * acc[mi][0] + acc[mi][1] * acc[mi][1]
               + acc[mi][2] * acc[mi][2] + acc[mi][3] * acc[mi][3];
#pragma unroll
      for (int cc = 0; cc < 4; cc++) {
        float s = red16(ss[cc]);
        sc[cc] = 1.f / fmaxf(sqrtf(s), 1e-12f);
      }
    }
#pragma unroll
    for (int ni = 0; ni < 4; ni++)
#pragma unroll
      for (int reg = 0; reg < 4; reg++) {
        int m = m0 + wm * 64 + mi * 16 + qd * 4 + reg;
        int n = n0 + wn * 64 + ni * 16 + r;
        float a = acc[mi][ni][reg];
        if (MODE == 0) ((unsigned short*)Cv)[(size_t)m * N + n] = f2bf(a);
        else if (MODE == 1) ((float*)Cv)[(size_t)m * N + n] = a;
        else {
          if (qk) a *= sc[reg];
          if (n < 3072) ((unsigned short*)Cv)[(size_t)m * 3072 + n] = f2bf(a);
          else if (n < 3104) {
            int j = n - 3072;
            float bias = (j < 16) ? ba[j] : bbp[j - 16];
            float s = 1.f / (1.f + expf(-(a + bias)));
            if (j < 16) alphaF[(size_t)m * 16 + j] = s;
            else        betaF[(size_t)m * 16 + (j - 16)] = s;
          }
        }
      }
  }
}

// ================================================================ FALLBACK: R2 dscan (proven)
#define D_OFF_STHI 0
#define D_OFF_STLO 8192
#define D_OFF_K    16384
#define D_OFF_Q    24576
#define D_OFF_V    32768
#define D_OFF_KT   40960
#define D_OFF_MT   45056
#define D_OFF_GBF  53248
#define D_OFF_CTHI 57344
#define D_OFF_CTLO 67584
#define D_OFF_W    77824
#define D_OFF_U    86016
#define D_OFF_AB   102400
#define D_LDS_SIZE 104512

__global__ __launch_bounds__(512, 2) void dscan_k(const unsigned short* __restrict__ qkv,
                                                  const float* __restrict__ alphaF,
                                                  const float* __restrict__ betaF,
                                                  unsigned short* __restrict__ y) {
  extern __shared__ char smem[];
  const int bh = blockIdx.x;
  const int b = bh >> 4, h = bh & 15;
  const int tid = threadIdx.x, wid = tid >> 6, lane = tid & 63;
  const int r = lane & 15, qd = lane >> 4;

  float* abf = (float*)(smem + D_OFF_AB);

  auto stage_jobs = [&](int cn) {
    int buf = cn & 1;
    int tok0 = b * SEQ + cn * 32;
    int row = lane >> 3, s8 = lane & 7;
    int sx = ((s8 ^ (row & 7)) * 8);
    {
      int p = (wid < 4) ? wid : wid - 4;
      int colbase = (wid < 4) ? (1024 + h * 64) : (h * 64);
      int off = (wid < 4) ? D_OFF_K : D_OFF_Q;
      const unsigned short* src = qkv + (size_t)(tok0 + p * 8 + row) * 3072 + colbase + sx;
      unsigned short* dst = (unsigned short*)(smem + off + buf * 4096 + p * 1024) + lane * 8;
      GLD16(src, dst);
    }
    if (wid < 4) {
      int p = wid;
      const unsigned short* src = qkv + (size_t)(tok0 + p * 8 + row) * 3072 + 2048 + h * 64 + sx;
      unsigned short* dst = (unsigned short*)(smem + D_OFF_V + buf * 4096 + p * 1024) + lane * 8;
      GLD16(src, dst);
    }
  };

  auto ab_compute = [&](int cn) {
    int t = lane & 31;
    int tok = b * SEQ + cn * 32 + t;
    float av = alphaF[(size_t)tok * 16 + h];
    float bv = betaF[(size_t)tok * 16 + h];
    float p = av;
#pragma unroll
    for (int s = 1; s < 32; s <<= 1) {
      float o = __shfl_up(p, s, 32);
      if ((lane & 31) >= s) p *= o;
    }
    float ep = __shfl_up(p, 1, 32);
    if ((lane & 31) == 0) ep = 1.f;
    float* ap = abf + (cn & 3) * 132;
    if (lane < 32) {
      ap[0 + t] = ep;
      ap[32 + t] = p;
      ap[64 + t] = 1.0f / p;
      if (t == 31) ap[128] = p;
    } else {
      ap[96 + t] = bv;
    }
  };

  auto gram_do = [&](int cn) {
    if (wid < 3 || wid > 6) return;
    int buf = cn & 1;
    const char* Kn = smem + D_OFF_K + buf * 4096;
    const char* Qn = smem + D_OFF_Q + buf * 4096;
    const float* ap = abf + (cn & 3) * 132;
    bool kk = (wid <= 4);
    int g0 = (kk ? (wid - 3) : (wid - 5)) * 2;
#pragma unroll
    for (int j = 0; j < 2; ++j) {
      int g = g0 + j, gi = g >> 1, gt = g & 1;
      f32x4 acc = (f32x4){0.f, 0.f, 0.f, 0.f};
#pragma unroll
      for (int ks = 0; ks < 2; ++ks) {
        int o = ks * 64 + qd * 16;
        bf16x8s af = *(const bf16x8s*)(Kn + (gi * 16 + r) * 128 + (o ^ ((r & 7) << 4)));
        bf16x8s bf = kk
            ? *(const bf16x8s*)(Kn + (gt * 16 + r) * 128 + (o ^ ((r & 7) << 4)))
            : *(const bf16x8s*)(Qn + (gt * 16 + r) * 128 + (o ^ ((r & 7) << 4)));
        acc = __builtin_amdgcn_mfma_f32_16x16x32_bf16(af, bf, acc, 0, 0, 0);
      }
      int tl = gt * 16 + r;
      f32x4 ei4 = *(const f32x4*)&ap[64 + gi * 16 + qd * 4];
      if (kk) {
        float bt = ap[96 + tl], ept = ap[0 + tl];
        float* Mtp = (float*)(smem + D_OFF_MT + buf * 4096);
#pragma unroll
        for (int reg = 0; reg < 4; ++reg) {
          int i = gi * 16 + qd * 4 + reg;
          Mtp[i * 32 + tl] = (i < tl) ? bt * ept * ei4[reg] * acc[reg] : 0.f;
        }
      } else {
        float et = ap[32 + tl];
        unsigned short* Gp = (unsigned short*)(smem + D_OFF_GBF + buf * 2048);
#pragma unroll
        for (int reg = 0; reg < 4; ++reg) {
          int i = gi * 16 + qd * 4 + reg;
          float v = (i <= tl) ? et * ei4[reg] * acc[reg] : 0.f;
          Gp[tl * 32 + i] = f2bf(v);
        }
      }
    }
  };

  float sreg[8];
#pragma unroll
  for (int i = 0; i < 8; ++i) sreg[i] = 0.f;

  {
    uint4 z = (uint4){0u, 0u, 0u, 0u};
    *(uint4*)(smem + D_OFF_STHI + tid * 16) = z;
    *(uint4*)(smem + D_OFF_STLO + tid * 16) = z;
  }
  stage_jobs(0);
  if (wid == 0) ab_compute(0);
  else if (wid == 1) ab_compute(1);
  __syncthreads();
  gram_do(0);
  __syncthreads();

  const char* SThi = smem + D_OFF_STHI;
  const char* STlo = smem + D_OFF_STLO;

  for (int c = 0; c < 64; ++c) {
    const int cbuf = c & 1, cs = c & 3;
    if (c + 1 < 64) stage_jobs(c + 1);
    {
      int tt = wid >> 2, te = wid & 3;
      const char* Kc = smem + D_OFF_K + cbuf * 4096;
      f32x4 acc = (f32x4){0.f, 0.f, 0.f, 0.f};
#pragma unroll
      for (int ks = 0; ks < 2; ++ks) {
        int o = ks * 64 + qd * 16;
        bf16x8s af = *(const bf16x8s*)(Kc + (tt * 16 + r) * 128 + (o ^ ((r & 7) << 4)));
        bf16x8s bhv = *(const bf16x8s*)(SThi + (te * 16 + r) * 128 + (o ^ ((r & 7) << 4)));
        bf16x8s blv = *(const bf16x8s*)(STlo + (te * 16 + r) * 128 + (o ^ ((r & 7) << 4)));
        acc = __builtin_amdgcn_mfma_f32_16x16x32_bf16(af, bhv, acc, 0, 0, 0);
        acc = __builtin_amdgcn_mfma_f32_16x16x32_bf16(af, blv, acc, 0, 0, 0);
      }
      float* Wp = (float*)(smem + D_OFF_W);
#pragma unroll
      for (int reg = 0; reg < 4; ++reg)
        Wp[(tt * 16 + qd * 4 + reg) * 64 + te * 16 + r] = acc[reg];
    }
    if (c >= 1) {
      int cc = c - 1, buf = cc & 1;
      int ty = wid >> 2, te = wid & 3;
      const char* Gp = smem + D_OFF_GBF + buf * 2048;
      bf16x8s af = *(const bf16x8s*)(Gp + (ty * 16 + r) * 64 + qd * 16);
      bf16x8s bhv = *(const bf16x8s*)(smem + D_OFF_CTHI + buf * 5120 + (te * 16 + r) * 80 + qd * 16);
      bf16x8s blv = *(const bf16x8s*)(smem + D_OFF_CTLO + buf * 5120 + (te * 16 + r) * 80 + qd * 16);
      f32x4 acc = (f32x4){0.f, 0.f, 0.f, 0.f};
      acc = __builtin_amdgcn_mfma_f32_16x16x32_bf16(af, bhv, acc, 0, 0, 0);
      acc = __builtin_amdgcn_mfma_f32_16x16x32_bf16(af, blv, acc, 0, 0, 0);
      const float* Up = (const float*)(smem + D_OFF_U + buf * 8192);
      f32x4 e4 = *(const f32x4*)&abf[(cc & 3) * 132 + 32 + ty * 16 + qd * 4];
#pragma unroll
      for (int reg = 0; reg < 4; ++reg) {
        int t = ty * 16 + qd * 4 + reg, e = te * 16 + r;
        float yv = fmaf(e4[reg], Up[t * 64 + e], acc[reg]);
        y[(size_t)(b * SEQ + cc * 32 + t) * 1024 + h * 64 + e] = f2bf(yv);
      }
    }
    __syncthreads();

    if (wid == 0) {
      const float* Wp = (const float*)(smem + D_OFF_W);
      const char* Vb = smem + D_OFF_V + cbuf * 4096;
      const float* ap = abf + cs * 132;
      float vb = ap[96 + (lane & 31)];
      float vep = ap[0 + (lane & 31)];
      float d_[32], r_[32];
#pragma unroll
      for (int i = 0; i < 32; ++i) r_[i] = 0.f;
#pragma unroll
      for (int i = 0; i < 32; ++i) {
        float w = Wp[i * 64 + lane];
        unsigned short vx = *(const unsigned short*)(Vb + (i * 128 + ((lane * 2) ^ ((i & 7) << 4))));
        d_[i] = rdlane(vb, i) * fmaf(-rdlane(vep, i), w, bf2f(vx));
      }
      const float* Mtp = (const float*)(smem + D_OFF_MT + cbuf * 4096);
#pragma unroll
      for (int i = 0; i < 32; ++i) {
        float cv = d_[i] - r_[i];
        d_[i] = cv;
#pragma unroll
        for (int cb4 = 0; cb4 < 8; ++cb4) {
          if (cb4 * 4 + 3 > i) {
            f32x4 m4 = *(const f32x4*)&Mtp[i * 32 + cb4 * 4];
            r_[cb4 * 4 + 0] = fmaf(m4[0], cv, r_[cb4 * 4 + 0]);
            r_[cb4 * 4 + 1] = fmaf(m4[1], cv, r_[cb4 * 4 + 1]);
            r_[cb4 * 4 + 2] = fmaf(m4[2], cv, r_[cb4 * 4 + 2]);
            r_[cb4 * 4 + 3] = fmaf(m4[3], cv, r_[cb4 * 4 + 3]);
          }
        }
      }
      unsigned int ph[16], pl[16];
#pragma unroll
      for (int j = 0; j < 16; ++j) {
        unsigned short h0 = f2bf(d_[2 * j]), h1 = f2bf(d_[2 * j + 1]);
        ph[j] = (unsigned int)h0 | ((unsigned int)h1 << 16);
        float l0 = d_[2 * j] - bf2f(h0), l1 = d_[2 * j + 1] - bf2f(h1);
        pl[j] = (unsigned int)f2bf(l0) | ((unsigned int)f2bf(l1) << 16);
      }
      char* Ch = smem + D_OFF_CTHI + cbuf * 5120 + lane * 80;
      char* Cl = smem + D_OFF_CTLO + cbuf * 5120 + lane * 80;
#pragma unroll
      for (int k = 0; k < 4; ++k) {
        *(uint4*)(Ch + k * 16) = (uint4){ph[4 * k], ph[4 * k + 1], ph[4 * k + 2], ph[4 * k + 3]};
        *(uint4*)(Cl + k * 16) = (uint4){pl[4 * k], pl[4 * k + 1], pl[4 * k + 2], pl[4 * k + 3]};
      }
    } else {
      if (wid <= 4) {
        const char* Qc = smem + D_OFF_Q + cbuf * 4096;
        float* Up = (float*)(smem + D_OFF_U + cbuf * 8192);
#pragma unroll
        for (int j = 0; j < 2; ++j) {
          int u = (wid - 1) * 2 + j, tu = u >> 2, te = u & 3;
          f32x4 acc = (f32x4){0.f, 0.f, 0.f, 0.f};
#pragma unroll
          for (int ks = 0; ks < 2; ++ks) {
            int o = ks * 64 + qd * 16;
            bf16x8s af = *(const bf16x8s*)(Qc + (tu * 16 + r) * 128 + (o ^ ((r & 7) << 4)));
            bf16x8s bhv = *(const bf16x8s*)(SThi + (te * 16 + r) * 128 + (o ^ ((r & 7) << 4)));
            bf16x8s blv = *(const bf16x8s*)(STlo + (te * 16 + r) * 128 + (o ^ ((r & 7) << 4)));
            acc = __builtin_amdgcn_mfma_f32_16x16x32_bf16(af, bhv, acc, 0, 0, 0);
            acc = __builtin_amdgcn_mfma_f32_16x16x32_bf16(af, blv, acc, 0, 0, 0);
          }
#pragma unroll
          for (int reg = 0; reg < 4; ++reg)
            Up[(tu * 16 + qd * 4 + reg) * 64 + te * 16 + r] = acc[reg];
        }
      }
      if (c + 1 < 64) gram_do(c + 1);
      if (wid == 7) {
        const float* ap = abf + cs * 132;
        float vei = ap[64 + (lane & 31)];
        float e31 = ap[128];
        const char* Kc = smem + D_OFF_K + cbuf * 4096;
        unsigned short* KT = (unsigned short*)(smem + D_OFF_KT);
        unsigned int pk[16];
#pragma unroll
        for (int i = 0; i < 32; ++i) {
          unsigned short kv = *(const unsigned short*)(Kc + (i * 128 + ((lane * 2) ^ ((i & 7) << 4))));
          float f = bf2f(kv) * (e31 * rdlane(vei, i));
          unsigned short o = f2bf(f);
          if (i & 1) pk[i >> 1] |= ((unsigned int)o << 16);
          else       pk[i >> 1] = o;
        }
#pragma unroll
        for (int k = 0; k < 4; ++k)
          *(uint4*)((char*)KT + lane * 64 + k * 16) =
              (uint4){pk[4 * k], pk[4 * k + 1], pk[4 * k + 2], pk[4 * k + 3]};
      }
      if (wid == 2 && c + 2 < 64) ab_compute(c + 2);
    }
    __syncthreads();

    {
      float e31 = abf[cs * 132 + 128];
      const char* KT = smem + D_OFF_KT;
#pragma unroll
      for (int j = 0; j < 2; ++j) {
        int s = wid * 2 + j, td = s >> 2, te = s & 3;
        bf16x8s af = *(const bf16x8s*)(KT + (td * 16 + r) * 64 + qd * 16);
        bf16x8s bhv = *(const bf16x8s*)(smem + D_OFF_CTHI + cbuf * 5120 + (te * 16 + r) * 80 + qd * 16);
        bf16x8s blv = *(const bf16x8s*)(smem + D_OFF_CTLO + cbuf * 5120 + (te * 16 + r) * 80 + qd * 16);
        f32x4 acc = (f32x4){0.f, 0.f, 0.f, 0.f};
        acc = __builtin_amdgcn_mfma_f32_16x16x32_bf16(af, bhv, acc, 0, 0, 0);
        acc = __builtin_amdgcn_mfma_f32_16x16x32_bf16(af, blv, acc, 0, 0, 0);
#pragma unroll
        for (int reg = 0; reg < 4; ++reg) {
          int d = td * 16 + qd * 4 + reg, e = te * 16 + r;
          float sv = fmaf(e31, sreg[j * 4 + reg], acc[reg]);
          sreg[j * 4 + reg] = sv;
          unsigned short hi = f2bf(sv);
          float lo = sv - bf2f(hi);
          *(unsigned short*)(smem + D_OFF_STHI + e * 128 + ((d * 2) ^ ((e & 7) << 4))) = hi;
          *(unsigned short*)(smem + D_OFF_STLO + e * 128 + ((d * 2) ^ ((e & 7) << 4))) = f2bf(lo);
        }
      }
    }
    if (c + 1 < 64) gram_do(c + 1);
    __syncthreads();
  }

  {
    int cc = 63, buf = cc & 1;
    int ty = wid >> 2, te = wid & 3;
    const char* Gp = smem + D_OFF_GBF + buf * 2048;
    bf16x8s af = *(const bf16x8s*)(Gp + (ty * 16 + r) * 64 + qd * 16);
    bf16x8s bhv = *(const bf16x8s*)(smem + D_OFF_CTHI + buf * 5120 + (te * 16 + r) * 80 + qd * 16);
    bf16x8s blv = *(const bf16x8s*)(smem + D_OFF_CTLO + buf * 5120 + (te * 16 + r) * 80 + qd * 16);
    f32x4 acc = (f32x4){0.f, 0.f, 0.f, 0.f};
    acc = __builtin_amdgcn_mfma_f32_16x16x32_bf16(af, bhv, acc, 0, 0, 0);
    acc = __builtin_amdgcn_mfma_f32_16x16x32_bf16(af, blv, acc, 0, 0, 0);
    const float* Up = (const float*)(smem + D_OFF_U + buf * 8192);
    f32x4 e4 = *(const f32x4*)&abf[(cc & 3) * 132 + 32 + ty * 16 + qd * 4];
#pragma unroll
    for (int reg = 0; reg < 4; ++reg) {
      int t = ty * 16 + qd * 4 + reg, e = te * 16 + r;
      float yv = fmaf(e4[reg], Up[t * 64 + e], acc[reg]);
      y[(size_t)(b * SEQ + cc * 32 + t) * 1024 + h * 64 + e] = f2bf(yv);
    }
  }
}

// ================================================================ NEW PATH Kernel A: per-chunk prep
#define AK   0
#define AQ   4096
#define AV   8192
#define AMT  12288   // f32 [32][36]
#define AGS  16896   // us [32][40]
#define AKP  19456   // us [64][32] compact swz
#define AAB  24576   // f32 [136]
#define ASZ  25120

__global__ __launch_bounds__(256) void aprep_k(const unsigned short* __restrict__ qkv,
                                               const float* __restrict__ alphaF,
                                               const float* __restrict__ betaF,
                                               unsigned char* __restrict__ RbHi,
                                               unsigned char* __restrict__ RbLo,
                                               unsigned char* __restrict__ Kpg,
                                               unsigned char* __restrict__ Gg,
                                               float* __restrict__ wg,
                                               float* __restrict__ eing) {
  __shared__ __align__(16) char smA[ASZ];
  const int u = blockIdx.x;
  const int bh = u >> 6, c = u & 63;
  const int b = bh >> 4, h = bh & 15;
  const int tid = threadIdx.x, wid = tid >> 6, lane = tid & 63;
  const int r = lane & 15, qd = lane >> 4;
  float* ab = (float*)(smA + AAB);

  {
    int tok0 = b * SEQ + c * 32;
    int row = lane >> 3, s8 = lane & 7;
    int sx = ((s8 ^ (row & 7)) * 8);
    const unsigned short* base = qkv + (size_t)(tok0 + wid * 8 + row) * 3072 + h * 64 + sx;
    GLD16(base + 1024, smA + AK + wid * 1024 + lane * 16);
    GLD16(base,        smA + AQ + wid * 1024 + lane * 16);
    GLD16(base + 2048, smA + AV + wid * 1024 + lane * 16);
  }
  if (wid == 0) {
    int t = lane & 31;
    int tok = b * SEQ + c * 32 + t;
    float av = alphaF[(size_t)tok * 16 + h];
    float bv = betaF[(size_t)tok * 16 + h];
    float p = av;
#pragma unroll
    for (int s = 1; s < 32; s <<= 1) {
      float o = __shfl_up(p, s, 32);
      if ((lane & 31) >= s) p *= o;
    }
    float ep = __shfl_up(p, 1, 32);
    if ((lane & 31) == 0) ep = 1.f;
    if (lane < 32) {
      ab[0 + t] = ep;
      ab[32 + t] = p;
      ab[64 + t] = 1.0f / p;
      if (t == 31) ab[128] = p;
    } else {
      ab[96 + t] = bv;
    }
  }
  __syncthreads();

  const int sw = ((r & 7) << 4);
  if (wid < 2) {
    int gi = wid;
    float* Mtp = (float*)(smA + AMT);
    f32x4 ei4 = *(const f32x4*)&ab[64 + gi * 16 + qd * 4];
#pragma unroll
    for (int gt = 0; gt < 2; ++gt) {
      f32x4 acc = (f32x4){0.f, 0.f, 0.f, 0.f};
#pragma unroll
      for (int ks = 0; ks < 2; ++ks) {
        int o = ks * 64 + qd * 16;
        bf16x8s af = *(const bf16x8s*)(smA + AK + (gi * 16 + r) * 128 + (o ^ sw));
        bf16x8s bf = *(const bf16x8s*)(smA + AK + (gt * 16 + r) * 128 + (o ^ sw));
        acc = __builtin_amdgcn_mfma_f32_16x16x32_bf16(af, bf, acc, 0, 0, 0);
      }
      int tl = gt * 16 + r;
      float bep = ab[96 + tl] * ab[0 + tl];
#pragma unroll
      for (int reg = 0; reg < 4; ++reg) {
        int i = gi * 16 + qd * 4 + reg;
        Mtp[i * 36 + tl] = (i < tl) ? bep * ei4[reg] * acc[reg] : 0.f;
      }
    }
  } else {
    int gi = wid - 2;
    unsigned short* Gp = (unsigned short*)(smA + AGS);
    f32x4 ei4 = *(const f32x4*)&ab[64 + gi * 16 + qd * 4];
#pragma unroll
    for (int gt = 0; gt < 2; ++gt) {
      f32x4 acc = (f32x4){0.f, 0.f, 0.f, 0.f};
#pragma unroll
      for (int ks = 0; ks < 2; ++ks) {
        int o = ks * 64 + qd * 16;
        bf16x8s af = *(const bf16x8s*)(smA + AK + (gi * 16 + r) * 128 + (o ^ sw));
        bf16x8s bf = *(const bf16x8s*)(smA + AQ + (gt * 16 + r) * 128 + (o ^ sw));
        acc = __builtin_amdgcn_mfma_f32_16x16x32_bf16(af, bf, acc, 0, 0, 0);
      }
      int tl = gt * 16 + r;
      float et = ab[32 + tl];
#pragma unroll
      for (int reg = 0; reg < 4; ++reg) {
        int i = gi * 16 + qd * 4 + reg;
        float v = (i <= tl) ? et * ei4[reg] * acc[reg] : 0.f;
        Gp[tl * 40 + i] = f2bf(v);
      }
    }
    {
      int i0 = (wid - 2) * 16;
      float e31 = ab[128];
#pragma unroll
      for (int ii = 0; ii < 16; ++ii) {
        int i = i0 + ii;
        unsigned short kv = *(const unsigned short*)(smA + AK + i * 128 + ((lane * 2) ^ ((i & 7) << 4)));
        float f = bf2f(kv) * (e31 * ab[64 + i]);
        *(unsigned short*)(smA + AKP + lane * 64 + ((i * 2) ^ ((lane & 3) << 4))) = f2bf(f);
      }
    }
  }
  __syncthreads();

  if (wid < 2) {
    float d_[32], r_[32];
#pragma unroll
    for (int i = 0; i < 32; ++i) r_[i] = 0.f;
#pragma unroll
    for (int i = 0; i < 32; ++i) {
      unsigned short xv;
      if (wid == 0) xv = *(const unsigned short*)(smA + AK + i * 128 + ((lane * 2) ^ ((i & 7) << 4)));
      else          xv = *(const unsigned short*)(smA + AV + i * 128 + ((lane * 2) ^ ((i & 7) << 4)));
      float scv = (wid == 0) ? ab[96 + i] * ab[0 + i] : ab[96 + i];
      d_[i] = scv * bf2f(xv);
    }
    const float* Mtp = (const float*)(smA + AMT);
#pragma unroll
    for (int i = 0; i < 32; ++i) {
      float cv = d_[i] - r_[i];
      d_[i] = cv;
#pragma unroll
      for (int cb4 = 0; cb4 < 8; ++cb4) {
        if (cb4 * 4 + 3 > i) {
          f32x4 m4 = *(const f32x4*)&Mtp[i * 36 + cb4 * 4];
          r_[cb4 * 4 + 0] = fmaf(m4[0], cv, r_[cb4 * 4 + 0]);
          r_[cb4 * 4 + 1] = fmaf(m4[1], cv, r_[cb4 * 4 + 1]);
          r_[cb4 * 4 + 2] = fmaf(m4[2], cv, r_[cb4 * 4 + 2]);
          r_[cb4 * 4 + 3] = fmaf(m4[3], cv, r_[cb4 * 4 + 3]);
        }
      }
    }
    if (wid == 0) {
      size_t ub = (size_t)u * 4096;
#pragma unroll
      for (int t = 0; t < 32; ++t) {
        unsigned short hi = f2bf(d_[t]);
        float lo = d_[t] - bf2f(hi);
        int off = t * 128 + ((lane * 2) ^ ((t & 7) << 4));
        *(unsigned short*)(RbHi + ub + off) = hi;
        *(unsigned short*)(RbLo + ub + off) = f2bf(lo);
      }
    } else {
      float* wp = wg + (size_t)u * 2048;
#pragma unroll
      for (int t = 0; t < 32; ++t) wp[t * 64 + lane] = d_[t];
    }
  } else if (wid == 2) {
    const char* s = smA + AGS + lane * 40;
    unsigned char* dG = Gg + (size_t)u * 2560 + lane * 40;
#pragma unroll
    for (int k2 = 0; k2 < 5; ++k2)
      *(uint2*)(dG + k2 * 8) = *(const uint2*)(s + k2 * 8);
    if (lane < 32) eing[(size_t)u * 64 + lane] = ab[32 + lane];
    if (lane == 32) eing[(size_t)u * 64 + 32] = ab[128];
  } else {
    const char* s = smA + AKP;
    unsigned char* dK = Kpg + (size_t)u * 4096;
#pragma unroll
    for (int k2 = 0; k2 < 4; ++k2)
      *(uint4*)(dK + lane * 64 + k2 * 16) = *(const uint4*)(s + lane * 64 + k2 * 16);
  }
}

// ================================================================ NEW PATH Kernel B: serial combine
// 64 blocks (bh), 256 thr. Per chunk: C = w - Rb*Sin (overwrite wg with C image),
// S = e31*S + Kp*C; snapshot Sin image to Sing at even chunks.
#define BSH  0
#define BSL  8192
#define BRH  16384   // 2 x 4096
#define BRL  24576   // 2 x 4096
#define BKP  32768   // 2 x 4096
#define BW   40960   // 2 x 8192
#define BCTH 57344   // 4096  [64 e][32 t] swz(e&3) hi
#define BCTL 61440   // 4096
#define BSZ  65536

__global__ __launch_bounds__(256) void bcomb_k(const unsigned char* __restrict__ RbHi,
                                               const unsigned char* __restrict__ RbLo,
                                               const unsigned char* __restrict__ Kpg,
                                               float* __restrict__ wcg,
                                               const float* __restrict__ eing,
                                               unsigned char* __restrict__ Sing) {
  extern __shared__ char smB[];
  const int bh = blockIdx.x;
  const int u_base = bh * 64;
  const int tid = threadIdx.x, wid = tid >> 6, lane = tid & 63;
  const int r = lane & 15, qd = lane >> 4;
  const int sw7 = ((r & 7) << 4), sw3 = ((r & 3) << 4);

  auto stageB = [&](int cn, int buf) {
    int u = u_base + cn;
    for (int j = wid; j < 20; j += 4) {
      const unsigned char* src; char* dst;
      if (j < 4)       { src = RbHi + (size_t)u * 4096 + j * 1024;       dst = smB + BRH + buf * 4096 + j * 1024; }
      else if (j < 8)  { src = RbLo + (size_t)u * 4096 + (j - 4) * 1024; dst = smB + BRL + buf * 4096 + (j - 4) * 1024; }
      else if (j < 12) { src = Kpg + (size_t)u * 4096 + (j - 8) * 1024;  dst = smB + BKP + buf * 4096 + (j - 8) * 1024; }
      else             { src = (const unsigned char*)wcg + (size_t)u * 8192 + (j - 12) * 1024;
                         dst = smB + BW + buf * 8192 + (j - 12) * 1024; }
      GLD16(src + lane * 16, dst + lane * 16);
    }
  };

#pragma unroll
  for (int k = 0; k < 4; ++k)
    *(uint4*)(smB + tid * 64 + k * 16) = (uint4){0u, 0u, 0u, 0u};
  float sreg[16];
#pragma unroll
  for (int i = 0; i < 16; ++i) sreg[i] = 0.f;

  stageB(0, 0);
  float e31c = eing[(size_t)u_base * 64 + 32];
  __syncthreads();

  for (int c = 0; c < 64; ++c) {
    const int buf = c & 1;
    const int u = u_base + c;
    float e31n = 0.f;
    if (c + 1 < 64) {
      stageB(c + 1, buf ^ 1);
      e31n = eing[(size_t)(u + 1) * 64 + 32];
    }
    if (!(c & 1)) {
#pragma unroll
      for (int k = 0; k < 4; ++k)
        *(uint4*)(Sing + (size_t)(u >> 1) * 16384 + k * 4096 + tid * 16) =
            *(const uint4*)(smB + k * 4096 + tid * 16);
    }
    // P1 = Rb * Sin^T (3-term hi/lo)
    f32x4 accP[2];
#pragma unroll
    for (int tt = 0; tt < 2; ++tt) {
      accP[tt] = (f32x4){0.f, 0.f, 0.f, 0.f};
#pragma unroll
      for (int ks = 0; ks < 2; ++ks) {
        int o = ks * 64 + qd * 16;
        bf16x8s sh = *(const bf16x8s*)(smB + BSH + (wid * 16 + r) * 128 + (o ^ sw7));
        bf16x8s sl = *(const bf16x8s*)(smB + BSL + (wid * 16 + r) * 128 + (o ^ sw7));
        bf16x8s rh = *(const bf16x8s*)(smB + BRH + buf * 4096 + (tt * 16 + r) * 128 + (o ^ sw7));
        bf16x8s rl = *(const bf16x8s*)(smB + BRL + buf * 4096 + (tt * 16 + r) * 128 + (o ^ sw7));
        accP[tt] = __builtin_amdgcn_mfma_f32_16x16x32_bf16(rh, sh, accP[tt], 0, 0, 0);
        accP[tt] = __builtin_amdgcn_mfma_f32_16x16x32_bf16(rh, sl, accP[tt], 0, 0, 0);
        accP[tt] = __builtin_amdgcn_mfma_f32_16x16x32_bf16(rl, sh, accP[tt], 0, 0, 0);
      }
    }
    // C = w - P1 -> CT compact
    {
      const float* wp = (const float*)(smB + BW + buf * 8192);
#pragma unroll
      for (int tt = 0; tt < 2; ++tt)
#pragma unroll
        for (int reg = 0; reg < 4; ++reg) {
          int t = tt * 16 + qd * 4 + reg, e = wid * 16 + r;
          float cv = wp[t * 64 + e] - accP[tt][reg];
          unsigned short hi = f2bf(cv);
          int off = e * 64 + ((t * 2) ^ ((e & 3) << 4));
          *(unsigned short*)(smB + BCTH + off) = hi;
          *(unsigned short*)(smB + BCTL + off) = f2bf(cv - bf2f(hi));
        }
    }
    __syncthreads();
    // C image -> global (overwrite wg[u])
    *(uint4*)((unsigned char*)wcg + (size_t)u * 8192 + tid * 16) =
        *(const uint4*)(smB + BCTH + tid * 16);
    *(uint4*)((unsigned char*)wcg + (size_t)u * 8192 + 4096 + tid * 16) =
        *(const uint4*)(smB + BCTL + tid * 16);
    // S = e31*S + Kp*C
#pragma unroll
    for (int j = 0; j < 4; ++j) {
      f32x4 acc = (f32x4){0.f, 0.f, 0.f, 0.f};
      bf16x8s af = *(const bf16x8s*)(smB + BKP + buf * 4096 + (wid * 16 + r) * 64 + ((qd * 16) ^ sw3));
      bf16x8s ch = *(const bf16x8s*)(smB + BCTH + (j * 16 + r) * 64 + ((qd * 16) ^ sw3));
      bf16x8s cl = *(const bf16x8s*)(smB + BCTL + (j * 16 + r) * 64 + ((qd * 16) ^ sw3));
      acc = __builtin_amdgcn_mfma_f32_16x16x32_bf16(af, ch, acc, 0, 0, 0);
      acc = __builtin_amdgcn_mfma_f32_16x16x32_bf16(af, cl, acc, 0, 0, 0);
#pragma unroll
      for (int reg = 0; reg < 4; ++reg) {
        int d = wid * 16 + qd * 4 + reg, e = j * 16 + r;
        float sv = fmaf(e31c, sreg[j * 4 + reg], acc[reg]);
        sreg[j * 4 + reg] = sv;
        unsigned short hi = f2bf(sv);
        int off = e * 128 + ((d * 2) ^ ((e & 7) << 4));
        *(unsigned short*)(smB + BSH + off) = hi;
        *(unsigned short*)(smB + BSL + off) = f2bf(sv - bf2f(hi));
      }
    }
    e31c = e31n;
    __syncthreads();
  }
}

// ================================================================ NEW PATH Kernel C: chunk-pair output
// 2048 blocks (bh x pair). Y(c0) from SinA; SinB = e31*SinA + Kp*C0 (in-place); Y(c1) from SinB.
#define XSH  0        // 8192 SinA hi image (becomes SinB)
#define XSL  8192
#define XQ   16384    // 2 x 4096
#define XC   24576    // 2 x 8192 (hi 4096 + lo 4096 per chunk)
#define XG   40960    // 2 x 2560
#define XKP  46080    // 4096
#define XSZ  50176

__global__ __launch_bounds__(256) void cout2_k(const unsigned short* __restrict__ qkv,
                                               const float* __restrict__ wcg,
                                               const unsigned char* __restrict__ Gg,
                                               const unsigned char* __restrict__ Kpg,
                                               const float* __restrict__ eing,
                                               const unsigned char* __restrict__ Sing,
                                               unsigned short* __restrict__ y) {
  __shared__ __align__(16) char smC[XSZ];
  const int p = blockIdx.x;
  const int bh = p >> 5, pr = p & 31;
  const int b = bh >> 4, h = bh & 15;
  const int u0 = bh * 64 + pr * 2;
  const int tid = threadIdx.x, wid = tid >> 6, lane = tid & 63;
  const int r = lane & 15, qd = lane >> 4;
  const int sw7 = ((r & 7) << 4), sw3 = ((r & 3) << 4);
  const int tok0 = b * SEQ + pr * 64;

  for (int j = wid; j < 44; j += 4) {
    if (j < 16) {
      GLD16(Sing + (size_t)(u0 >> 1) * 16384 + j * 1024 + lane * 16,
            smC + XSH + j * 1024 + lane * 16);
    } else if (j < 24) {
      int q = (j - 16) >> 2, pt = (j - 16) & 3;
      int row = lane >> 3, s8 = lane & 7;
      int sx = ((s8 ^ (row & 7)) * 8);
      const unsigned short* src = qkv + (size_t)(tok0 + q * 32 + pt * 8 + row) * 3072 + h * 64 + sx;
      GLD16(src, smC + XQ + q * 4096 + pt * 1024 + lane * 16);
    } else if (j < 40) {
      int q = (j - 24) >> 3, pt = (j - 24) & 7;
      GLD16((const unsigned char*)wcg + (size_t)(u0 + q) * 8192 + pt * 1024 + lane * 16,
            smC + XC + q * 8192 + pt * 1024 + lane * 16);
    } else {
      GLD16(Kpg + (size_t)u0 * 4096 + (j - 40) * 1024 + lane * 16,
            smC + XKP + (j - 40) * 1024 + lane * 16);
    }
  }
  if (wid < 2) {
    const unsigned char* src = Gg + (size_t)(u0 + wid) * 2560;
    char* dst = smC + XG + wid * 2560;
    GLD16(src + lane * 16, dst + lane * 16);
    GLD16(src + 1024 + lane * 16, dst + 1024 + lane * 16);
    GLD4(src + 2048 + lane * 4, dst + 2048 + lane * 4);
    GLD4(src + 2304 + lane * 4, dst + 2304 + lane * 4);
  }
  __syncthreads();

  // ---- phase 1a: Y(c0) + accS (reads only) ----
  f32x4 accS[4];
#pragma unroll
  for (int half = 0; half < 1; ++half) {
    f32x4 accU[2], accG[2];
#pragma unroll
    for (int tt = 0; tt < 2; ++tt) {
      accU[tt] = (f32x4){0.f, 0.f, 0.f, 0.f};
#pragma unroll
      for (int ks = 0; ks < 2; ++ks) {
        int o = ks * 64 + qd * 16;
        bf16x8s sh = *(const bf16x8s*)(smC + XSH + (wid * 16 + r) * 128 + (o ^ sw7));
        bf16x8s sl = *(const bf16x8s*)(smC + XSL + (wid * 16 + r) * 128 + (o ^ sw7));
        bf16x8s qa = *(const bf16x8s*)(smC + XQ + (tt * 16 + r) * 128 + (o ^ sw7));
        accU[tt] = __builtin_amdgcn_mfma_f32_16x16x32_bf16(qa, sh, accU[tt], 0, 0, 0);
        accU[tt] = __builtin_amdgcn_mfma_f32_16x16x32_bf16(qa, sl, accU[tt], 0, 0, 0);
      }
      bf16x8s ga = *(const bf16x8s*)(smC + XG + (tt * 16 + r) * 80 + qd * 16);
      bf16x8s ch = *(const bf16x8s*)(smC + XC + (wid * 16 + r) * 64 + ((qd * 16) ^ sw3));
      bf16x8s cl = *(const bf16x8s*)(smC + XC + 4096 + (wid * 16 + r) * 64 + ((qd * 16) ^ sw3));
      accG[tt] = (f32x4){0.f, 0.f, 0.f, 0.f};
      accG[tt] = __builtin_amdgcn_mfma_f32_16x16x32_bf16(ga, ch, accG[tt], 0, 0, 0);
      accG[tt] = __builtin_amdgcn_mfma_f32_16x16x32_bf16(ga, cl, accG[tt], 0, 0, 0);
    }
#pragma unroll
    for (int tt = 0; tt < 2; ++tt) {
      f32x4 e4 = *(const f32x4*)&eing[(size_t)u0 * 64 + tt * 16 + qd * 4];
#pragma unroll
      for (int reg = 0; reg < 4; ++reg) {
        int t = tt * 16 + qd * 4 + reg, e = wid * 16 + r;
        y[(size_t)(tok0 + t) * 1024 + h * 64 + e] =
            f2bf(fmaf(e4[reg], accU[tt][reg], accG[tt][reg]));
      }
    }
    // accS = Kp(c0) * C(c0)
#pragma unroll
    for (int j = 0; j < 4; ++j) {
      accS[j] = (f32x4){0.f, 0.f, 0.f, 0.f};
      bf16x8s af = *(const bf16x8s*)(smC + XKP + (wid * 16 + r) * 64 + ((qd * 16) ^ sw3));
      bf16x8s ch = *(const bf16x8s*)(smC + XC + (j * 16 + r) * 64 + ((qd * 16) ^ sw3));
      bf16x8s cl = *(const bf16x8s*)(smC + XC + 4096 + (j * 16 + r) * 64 + ((qd * 16) ^ sw3));
      accS[j] = __builtin_amdgcn_mfma_f32_16x16x32_bf16(af, ch, accS[j], 0, 0, 0);
      accS[j] = __builtin_amdgcn_mfma_f32_16x16x32_bf16(af, cl, accS[j], 0, 0, 0);
    }
  }
  __syncthreads();
  // ---- phase 1b: in-place SinB = e31*SinA + accS ----
  {
    float e31 = eing[(size_t)u0 * 64 + 32];
#pragma unroll
    for (int j = 0; j < 4; ++j)
#pragma unroll
      for (int reg = 0; reg < 4; ++reg) {
        int d = wid * 16 + qd * 4 + reg, e = j * 16 + r;
        int off = e * 128 + ((d * 2) ^ ((e & 7) << 4));
        float sA = bf2f(*(const unsigned short*)(smC + XSH + off)) +
                   bf2f(*(const unsigned short*)(smC + XSL + off));
        float sv = fmaf(e31, sA, accS[j][reg]);
        unsigned short hi = f2bf(sv);
        *(unsigned short*)(smC + XSH + off) = hi;
        *(unsigned short*)(smC + XSL + off) = f2bf(sv - bf2f(hi));
      }
  }
  __syncthreads();
  // ---- phase 2: Y(c1) from SinB ----
  {
    f32x4 accU[2], accG[2];
#pragma unroll
    for (int tt = 0; tt < 2; ++tt) {
      accU[tt] = (f32x4){0.f, 0.f, 0.f, 0.f};
#pragma unroll
      for (int ks = 0; ks < 2; ++ks) {
        int o = ks * 64 + qd * 16;
        bf16x8s sh = *(const bf16x8s*)(smC + XSH + (wid * 16 + r) * 128 + (o ^ sw7));
        bf16x8s sl = *(const bf16x8s*)(smC + XSL + (wid * 16 + r) * 128 + (o ^ sw7));
        bf16x8s qa = *(const bf16x8s*)(smC + XQ + 4096 + (tt * 16 + r) * 128 + (o ^ sw7));
        accU[tt] = __builtin_amdgcn_mfma_f32_16x16x32_bf16(qa, sh, accU[tt], 0, 0, 0);
        accU[tt] = __builtin_amdgcn_mfma_f32_16x16x32_bf16(qa, sl, accU[tt], 0, 0, 0);
      }
      bf16x8s ga = *(const bf16x8s*)(smC + XG + 2560 + (tt * 16 + r) * 80 + qd * 16);
      bf16x8s ch = *(const bf16x8s*)(smC + XC + 8192 + (wid * 16 + r) * 64 + ((qd * 16) ^ sw3));
      bf16x8s cl = *(const bf16x8s*)(smC + XC + 8192 + 4096 + (wid * 16 + r) * 64 + ((qd * 16) ^ sw3));
      accG[tt] = (f32x4){0.f, 0.f, 0.f, 0.f};
      accG[tt] = __builtin_amdgcn_mfma_f32_16x16x32_bf16(ga, ch, accG[tt], 0, 0, 0);
      accG[tt] = __builtin_amdgcn_mfma_f32_16x16x32_bf16(ga, cl, accG[tt], 0, 0, 0);
    }
#pragma unroll
    for (int tt = 0; tt < 2; ++tt) {
      f32x4 e4 = *(const f32x4*)&eing[(size_t)(u0 + 1) * 64 + tt * 16 + qd * 4];
#pragma unroll
      for (int reg = 0; reg < 4; ++reg) {
        int t = tt * 16 + qd * 4 + reg, e = wid * 16 + r;
        y[(size_t)(tok0 + 32 + t) * 1024 + h * 64 + e] =
            f2bf(fmaf(e4[reg], accU[tt][reg], accG[tt][reg]));
      }
    }
  }
}

// ---------------------------------------------------------------- rmsnorm*gate
__global__ __launch_bounds__(256) void rmsgate_k(const unsigned short* __restrict__ y,
                                                 const unsigned short* __restrict__ gl,
                                                 const float* __restrict__ gnorm,
                                                 unsigned short* __restrict__ z) {
  __shared__ float red[4];
  int row = blockIdx.x, tid = threadIdx.x;
  size_t base = (size_t)row * 1024 + tid * 4;
  uint2 yv = *(const uint2*)&y[base];
  float f0 = bf2f((unsigned short)(yv.x & 0xffff)), f1 = bf2f((unsigned short)(yv.x >> 16));
  float f2 = bf2f((unsigned short)(yv.y & 0xffff)), f3 = bf2f((unsigned short)(yv.y >> 16));
  float ss = f0 * f0 + f1 * f1 + f2 * f2 + f3 * f3;
#pragma unroll
  for (int s = 1; s < 64; s <<= 1) ss += __shfl_xor(ss, s);
  if ((tid & 63) == 0) red[tid >> 6] = ss;
  __syncthreads();
  ss = red[0] + red[1] + red[2] + red[3];
  float rms = rsqrtf(ss * (1.0f / 1024.0f) + 1e-5f);
  uint2 gv = *(const uint2*)&gl[base];
  float4 gn = *(const float4*)&gnorm[tid * 4];
  float g[4] = {bf2f((unsigned short)(gv.x & 0xffff)), bf2f((unsigned short)(gv.x >> 16)),
                bf2f((unsigned short)(gv.y & 0xffff)), bf2f((unsigned short)(gv.y >> 16))};
  float gnv[4] = {gn.x, gn.y, gn.z, gn.w};
  float fv[4] = {f0, f1, f2, f3};
  unsigned short o[4];
#pragma unroll
  for (int jj = 0; jj < 4; jj++) {
    float gate = g[jj] / (1.f + expf(-g[jj]));
    o[jj] = f2bf(fv[jj] * rms * gnv[jj] * gate);
  }
  uint2 ov;
  ov.x = (unsigned int)o[0] | ((unsigned int)o[1] << 16);
  ov.y = (unsigned int)o[2] | ((unsigned int)o[3] << 16);
  *(uint2*)&z[base] = ov;
}

// ---------------------------------------------------------------- launch
extern "C" void kernel_launch(void* const* d_in, const int* in_sizes, int n_in,
                              void* d_out, int out_size, void* d_ws, size_t ws_size,
                              hipStream_t stream) {
  const float* x     = (const float*)d_in[0];
  const float* Wq    = (const float*)d_in[1];
  const float* Wk    = (const float*)d_in[2];
  const float* Wv    = (const float*)d_in[3];
  const float* Wa    = (const float*)d_in[4];
  const float* ba    = (const float*)d_in[5];
  const float* Wb    = (const float*)d_in[6];
  const float* bb    = (const float*)d_in[7];
  const float* Wg    = (const float*)d_in[8];
  const float* Wo    = (const float*)d_in[9];
  const float* gnorm = (const float*)d_in[10];
  float* out = (float*)d_out;

  unsigned short* xbf    = (unsigned short*)d_ws;                 // 8192*1024
  unsigned short* Bt_qkv = xbf + (size_t)NTOK * 1024;             // 3200*1024
  unsigned short* Bt_g   = Bt_qkv + (size_t)NQKV * 1024;          // 1024*1024
  unsigned short* Bt_o   = Bt_g + (size_t)1024 * 1024;            // 1024*1024
  unsigned short* qkv    = Bt_o + (size_t)1024 * 1024;            // 8192*3072
  unsigned short* gatelin= qkv + (size_t)NTOK * 3072;             // 8192*1024
  unsigned short* ybuf   = gatelin + (size_t)NTOK * 1024;         // 8192*1024
  float* alphaF          = (float*)(ybuf + (size_t)NTOK * 1024);  // 8192*16
  float* betaF           = alphaF + (size_t)NTOK * 16;            // 8192*16
  unsigned short* zbuf   = xbf;

  // new-path buffers (aliases + appended region)
  unsigned char* RbHi = (unsigned char*)xbf;                       // alias (dead after GEMMs)
  unsigned char* RbLo = (unsigned char*)ybuf;                      // alias (dead until cout writes y)
  float* eing         = (float*)Bt_qkv;                            // alias (dead after qkv GEMM)
  unsigned char* Kpg  = (unsigned char*)(betaF + (size_t)NTOK * 16);     // +16.78 MB
  unsigned char* Gg   = Kpg + (size_t)NUNIT * 4096;                      // +10.49 MB
  float* wcg          = (float*)(Gg + (size_t)NUNIT * 2560);             // +33.55 MB (w, then C)
  unsigned char* Sing = (unsigned char*)wcg + (size_t)NUNIT * 8192;      // +33.55 MB
  const unsigned long long need_new = 206831616ull;
  const bool use_new = (ws_size >= need_new);

  static int inited = 0;
  if (!inited) {
    hipFuncSetAttribute((const void*)dscan_k,
                        hipFuncAttributeMaxDynamicSharedMemorySize, D_LDS_SIZE);
    hipFuncSetAttribute((const void*)bcomb_k,
                        hipFuncAttributeMaxDynamicSharedMemorySize, BSZ);
    inited = 1;
  }

  castx_k<<<NTOK * 1024 / 4 / 256, 256, 0, stream>>>(x, xbf, NTOK * 1024 / 4);
  dim3 tb(32, 8);
  transpose_k<<<dim3(32, 32), tb, 0, stream>>>(Wq, Bt_qkv, 1024, 1024);
  transpose_k<<<dim3(32, 32), tb, 0, stream>>>(Wk, Bt_qkv + (size_t)1024 * 1024, 1024, 1024);
  transpose_k<<<dim3(32, 32), tb, 0, stream>>>(Wv, Bt_qkv + (size_t)2048 * 1024, 1024, 1024);
  transpose_k<<<dim3(32, 32), tb, 0, stream>>>(Wg, Bt_g, 1024, 1024);
  transpose_k<<<dim3(32, 32), tb, 0, stream>>>(Wo, Bt_o, 1024, 1024);
  build_wabT<<<512, 256, 0, stream>>>(Wa, Wb, Bt_qkv + (size_t)3072 * 1024);

  gemm_bt<2><<<(NTOK / 128) * (NQKV / 128), 256, 0, stream>>>(
      xbf, Bt_qkv, qkv, NTOK, NQKV, 1024, ba, bb, alphaF, betaF);
  gemm_bt<0><<<(NTOK / 128) * (1024 / 128), 256, 0, stream>>>(
      xbf, Bt_g, gatelin, NTOK, 1024, 1024, nullptr, nullptr, nullptr, nullptr);

  if (use_new) {
    aprep_k<<<NUNIT, 256, 0, stream>>>(qkv, alphaF, betaF, RbHi, RbLo, Kpg, Gg, wcg, eing);
    bcomb_k<<<64, 256, BSZ, stream>>>(RbHi, RbLo, Kpg, wcg, eing, Sing);
    cout2_k<<<2048, 256, 0, stream>>>(qkv, wcg, Gg, Kpg, eing, Sing, ybuf);
  } else {
    dscan_k<<<64, 512, D_LDS_SIZE, stream>>>(qkv, alphaF, betaF, ybuf);
  }

  rmsgate_k<<<NTOK, 256, 0, stream>>>(ybuf, gatelin, gnorm, zbuf);
  gemm_bt<1><<<(NTOK / 128) * (1024 / 128), 256, 0, stream>>>(
      zbuf, Bt_o, out, NTOK, 1024, 1024, nullptr, nullptr, nullptr, nullptr);
}